// Round 1
// baseline (6529.449 us; speedup 1.0000x reference)
//
#include <hip/hip_runtime.h>
#include <math.h>

// Problem constants (PMS_1): B=4, C=64, H=W=128
constexpr int B = 4, C = 64, H = 128, W = 128;
constexpr int HW = H * W;
constexpr size_t PLANE = (size_t)HW;          // 16384
constexpr size_t CHW   = (size_t)C * HW;      // 1,048,576
constexpr size_t TOT   = (size_t)B * CHW;     // 4,194,304
constexpr float SCALE  = 1.0f / 24.0f;        // 1/sqrt(C*9)

// ---------------------------------------------------------------------------
// Direct conv, fp32. Tile: 16x32 pixels x 16 ocs per block, 256 threads.
// Per-thread: 4 horiz pixels x 8 ocs = 32 accumulators.
// ACT: 0=none, 1=relu, 2=lrelu(0.01). cond: per (b,ic) input scale or null.
// res: pointer added to output (residual / accumulate) or null.
// ---------------------------------------------------------------------------
template <int K, int ACT>
__global__ __launch_bounds__(256) void conv_kernel(
    const float* __restrict__ in, const float* __restrict__ wgt,
    const float* __restrict__ bias, const float* __restrict__ cond,
    const float* __restrict__ res, float* __restrict__ out, float wscale)
{
    constexpr int TH = 16, TW = 32, KK = K * K, PADK = K / 2;
    constexpr int IH = TH + K - 1, IW = TW + K - 1, IWP = IW + 1; // odd stride
    __shared__ float s_in[4][IH][IWP];
    __shared__ float s_w[4][16][KK];

    const int tid = threadIdx.x;
    const int tile = blockIdx.x;            // 0..31
    const int ty = tile >> 2, tx = tile & 3;
    const int y0 = ty * TH, x0 = tx * TW;
    const int ocb = blockIdx.y * 16;
    const int b = blockIdx.z;

    const int ocg  = tid & 1;               // 2 oc-groups of 8
    const int pg   = tid >> 1;              // 128 pixel-groups
    const int prow = pg >> 3;               // 0..15
    const int pcol = (pg & 7) << 2;         // 0,4,...,28

    float acc[8][4];
#pragma unroll
    for (int u = 0; u < 8; ++u)
#pragma unroll
        for (int p = 0; p < 4; ++p) acc[u][p] = 0.f;

    for (int ic0 = 0; ic0 < C; ic0 += 4) {
        __syncthreads();
        // stage input (with halo, zero-padded, cond-scaled)
        for (int idx = tid; idx < 4 * IH * IW; idx += 256) {
            int icl = idx / (IH * IW);
            int rem = idx - icl * (IH * IW);
            int r = rem / IW;
            int cix = rem - r * IW;
            int gy = y0 + r - PADK, gx = x0 + cix - PADK;
            float v = 0.f;
            if (gy >= 0 && gy < H && gx >= 0 && gx < W)
                v = in[(size_t)(b * C + ic0 + icl) * PLANE + (size_t)gy * W + gx];
            if (cond) v *= cond[b * C + ic0 + icl];
            s_in[icl][r][cix] = v;
        }
        // stage weights for 16 ocs x 4 ics
        for (int idx = tid; idx < 4 * 16 * KK; idx += 256) {
            int icl = idx / (16 * KK);
            int rem = idx - icl * (16 * KK);
            int o = rem / KK;
            int kpos = rem - o * KK;
            s_w[icl][o][kpos] = wgt[((size_t)(ocb + o) * C + ic0 + icl) * KK + kpos];
        }
        __syncthreads();

#pragma unroll
        for (int icl = 0; icl < 4; ++icl) {
#pragma unroll
            for (int kh = 0; kh < K; ++kh) {
#pragma unroll
                for (int kw = 0; kw < K; ++kw) {
                    float i0 = s_in[icl][prow + kh][pcol + kw + 0];
                    float i1 = s_in[icl][prow + kh][pcol + kw + 1];
                    float i2 = s_in[icl][prow + kh][pcol + kw + 2];
                    float i3 = s_in[icl][prow + kh][pcol + kw + 3];
#pragma unroll
                    for (int u = 0; u < 8; ++u) {
                        float wv = s_w[icl][ocg * 8 + u][kh * K + kw];
                        acc[u][0] = fmaf(i0, wv, acc[u][0]);
                        acc[u][1] = fmaf(i1, wv, acc[u][1]);
                        acc[u][2] = fmaf(i2, wv, acc[u][2]);
                        acc[u][3] = fmaf(i3, wv, acc[u][3]);
                    }
                }
            }
        }
    }

    const int gy = y0 + prow;
#pragma unroll
    for (int u = 0; u < 8; ++u) {
        int oc = ocb + ocg * 8 + u;
        float bv = bias ? bias[oc] : 0.f;
        size_t base = (size_t)(b * C + oc) * PLANE + (size_t)gy * W + x0 + pcol;
#pragma unroll
        for (int p = 0; p < 4; ++p) {
            float v = fmaf(acc[u][p], wscale, bv);
            if (ACT == 1) v = fmaxf(v, 0.f);
            if (ACT == 2) v = v > 0.f ? v : 0.01f * v;
            if (res) v += res[base + p];
            out[base + p] = v;
        }
    }
}

// ---------------------------------------------------------------------------
// Per-(b,c) max & mean over the 128x128 plane. One block per (b,c).
// ---------------------------------------------------------------------------
__global__ __launch_bounds__(256) void pool_kernel(
    const float* __restrict__ o, float* __restrict__ mx, float* __restrict__ av)
{
    const int bc = blockIdx.x;
    const float* p = o + (size_t)bc * PLANE;
    const int tid = threadIdx.x;
    float m = -INFINITY, s = 0.f;
    for (int i = tid; i < HW; i += 256) {
        float v = p[i];
        m = fmaxf(m, v);
        s += v;
    }
#pragma unroll
    for (int off = 32; off > 0; off >>= 1) {
        m = fmaxf(m, __shfl_down(m, off));
        s += __shfl_down(s, off);
    }
    __shared__ float sm[4], ss[4];
    if ((tid & 63) == 0) { sm[tid >> 6] = m; ss[tid >> 6] = s; }
    __syncthreads();
    if (tid == 0) {
        m = fmaxf(fmaxf(sm[0], sm[1]), fmaxf(sm[2], sm[3]));
        s = ss[0] + ss[1] + ss[2] + ss[3];
        mx[bc] = m;
        av[bc] = s * (1.f / HW);
    }
}

// ---------------------------------------------------------------------------
// Channel attention + FC1 gate: Cg[b,c]. One block, 256 threads.
// se(z) = caw2 @ relu(caw1 @ z); xll = sigmoid(se(mx)+se(av));
// Cg = fw1*(fw0*xll + fb0) + fb1
// ---------------------------------------------------------------------------
__global__ __launch_bounds__(256) void cg_kernel(
    const float* __restrict__ mx, const float* __restrict__ av,
    const float* __restrict__ caw1, const float* __restrict__ caw2,
    const float* __restrict__ fcw, const float* __restrict__ fcb,
    float* __restrict__ Cg)
{
    __shared__ float hid[2][4][4]; // which, b, h
    const int t = threadIdx.x;
    if (t < 32) {
        int which = t >> 4, b = (t >> 2) & 3, h = t & 3;
        const float* src = which ? av : mx;
        float s = 0.f;
        for (int i = 0; i < C; ++i) s += caw1[h * C + i] * src[b * C + i];
        hid[which][b][h] = fmaxf(s, 0.f);
    }
    __syncthreads();
    int b = t >> 6, c = t & 63;
    float s = 0.f;
#pragma unroll
    for (int h = 0; h < 4; ++h)
        s += caw2[c * 4 + h] * (hid[0][b][h] + hid[1][b][h]);
    float xll = 1.f / (1.f + expf(-s));
    Cg[t] = fcw[1] * (fcw[0] * xll + fcb[0]) + fcb[1];
}

// o = Cg[b,c] * acc   (elementwise, float4)
__global__ __launch_bounds__(256) void cgmul_kernel(
    const float* __restrict__ acc, const float* __restrict__ Cg, float* __restrict__ o)
{
    size_t i = (size_t)blockIdx.x * 256 + threadIdx.x;
    size_t e = i * 4;
    int bc = (int)(e / PLANE);
    float g = Cg[bc];
    float4 v = ((const float4*)acc)[i];
    v.x *= g; v.y *= g; v.z *= g; v.w *= g;
    ((float4*)o)[i] = v;
}

// out = o * map + x   (map broadcast over channels)
__global__ __launch_bounds__(256) void final_kernel(
    const float* __restrict__ o, const float* __restrict__ mapp,
    const float* __restrict__ x, float* __restrict__ out)
{
    size_t i = (size_t)blockIdx.x * 256 + threadIdx.x;
    size_t e = i * 4;
    size_t b = e / CHW;
    size_t pos = e % PLANE;
    float4 ov = ((const float4*)o)[i];
    float4 xv = ((const float4*)x)[i];
    float4 mv = ((const float4*)(mapp + b * PLANE))[pos >> 2];
    float4 r;
    r.x = fmaf(ov.x, mv.x, xv.x);
    r.y = fmaf(ov.y, mv.y, xv.y);
    r.z = fmaf(ov.z, mv.z, xv.z);
    r.w = fmaf(ov.w, mv.w, xv.w);
    ((float4*)out)[i] = r;
}

extern "C" void kernel_launch(void* const* d_in, const int* in_sizes, int n_in,
                              void* d_out, int out_size, void* d_ws, size_t ws_size,
                              hipStream_t stream)
{
    const float* x    = (const float*)d_in[0];
    const float* cf1  = (const float*)d_in[1];
    const float* cf2  = (const float*)d_in[2];
    const float* mapp = (const float*)d_in[3];
    const float* rw   = (const float*)d_in[4];
    const float* rb   = (const float*)d_in[5];
    const float* mw1  = (const float*)d_in[6];
    const float* mb1  = (const float*)d_in[7];
    const float* mw3  = (const float*)d_in[8];
    const float* mb3  = (const float*)d_in[9];
    const float* mw5  = (const float*)d_in[10];
    const float* mb5  = (const float*)d_in[11];
    const float* caw1 = (const float*)d_in[12];
    const float* caw2 = (const float*)d_in[13];
    const float* fcw  = (const float*)d_in[14];
    const float* fcb  = (const float*)d_in[15];
    float* out = (float*)d_out;

    float* ws      = (float*)d_ws;
    float* buf_o   = ws;
    float* buf_t   = ws + TOT;
    float* buf_acc = ws + 2 * TOT;
    float* st      = ws + 3 * TOT;
    float* mx = st, *av = st + 256, *Cg = st + 512;

    const dim3 cgrid(32, 4, B);
    const dim3 egrid((unsigned)(TOT / 1024));

    int mfe_j = 0;
    for (int i = 0; i < 9; ++i) {
        const float* condb = (i < 5) ? (cf1 + (size_t)i * 2 * B * C)
                                     : (cf2 + (size_t)(i - 5) * 2 * B * C);
        const float* in0 = (i == 0) ? x : buf_o;
        const float* rw0 = rw + (size_t)(i * 2 + 0) * C * C * 9;
        const float* rw1 = rw + (size_t)(i * 2 + 1) * C * C * 9;
        const float* rb0 = rb + (i * 2 + 0) * C;
        const float* rb1 = rb + (i * 2 + 1) * C;
        // r = relu(conv(o*cond0, rw0*SCALE) + rb0)
        conv_kernel<3, 1><<<cgrid, 256, 0, stream>>>(in0, rw0, rb0, condb, nullptr, buf_t, SCALE);
        // o = conv(r*cond1, rw1*SCALE) + rb1 + o
        conv_kernel<3, 0><<<cgrid, 256, 0, stream>>>(buf_t, rw1, rb1, condb + B * C, in0, buf_o, SCALE);

        if (i == 1 || i == 3 || i == 5 || i == 7 || i == 8) {
            int j = mfe_j++;
            const float* w10 = mw1 + (size_t)(j * 2 + 0) * C * C;
            const float* w11 = mw1 + (size_t)(j * 2 + 1) * C * C;
            const float* w30 = mw3 + (size_t)(j * 2 + 0) * C * C * 9;
            const float* w31 = mw3 + (size_t)(j * 2 + 1) * C * C * 9;
            const float* w50 = mw5 + (size_t)(j * 2 + 0) * C * C * 25;
            const float* w51 = mw5 + (size_t)(j * 2 + 1) * C * C * 25;
            const float* b10 = mb1 + (j * 2 + 0) * C, *b11 = mb1 + (j * 2 + 1) * C;
            const float* b30 = mb3 + (j * 2 + 0) * C, *b31 = mb3 + (j * 2 + 1) * C;
            const float* b50 = mb5 + (j * 2 + 0) * C, *b51 = mb5 + (j * 2 + 1) * C;

            // x1 path (1x1): acc = conv(lrelu(conv(o)))
            conv_kernel<1, 2><<<cgrid, 256, 0, stream>>>(buf_o, w10, b10, nullptr, nullptr, buf_t, 1.f);
            conv_kernel<1, 0><<<cgrid, 256, 0, stream>>>(buf_t, w11, b11, nullptr, nullptr, buf_acc, 1.f);
            // x3 path (3x3): acc += ...
            conv_kernel<3, 2><<<cgrid, 256, 0, stream>>>(buf_o, w30, b30, nullptr, nullptr, buf_t, 1.f);
            conv_kernel<3, 0><<<cgrid, 256, 0, stream>>>(buf_t, w31, b31, nullptr, buf_acc, buf_acc, 1.f);
            // x5 path (5x5): acc += ...
            conv_kernel<5, 2><<<cgrid, 256, 0, stream>>>(buf_o, w50, b50, nullptr, nullptr, buf_t, 1.f);
            conv_kernel<5, 0><<<cgrid, 256, 0, stream>>>(buf_t, w51, b51, nullptr, buf_acc, buf_acc, 1.f);
            // channel attention gate
            pool_kernel<<<dim3(B * C), 256, 0, stream>>>(buf_o, mx, av);
            cg_kernel<<<1, 256, 0, stream>>>(mx, av, caw1 + j * 4 * C, caw2 + j * C * 4,
                                             fcw + j * 2, fcb + j * 2, Cg);
            // o = Cg * (x1+x3+x5)
            cgmul_kernel<<<egrid, 256, 0, stream>>>(buf_acc, Cg, buf_o);
        }
    }
    // out = o * map + x
    final_kernel<<<egrid, 256, 0, stream>>>(buf_o, mapp, x, out);
}

// Round 2
// 2017.617 us; speedup vs baseline: 3.2362x; 3.2362x over previous
//
#include <hip/hip_runtime.h>
#include <math.h>

// Problem constants (PMS_1): B=4, C=64, H=W=128
constexpr int B = 4, C = 64, H = 128, W = 128;
constexpr int HW = H * W;
constexpr size_t PLANE = (size_t)HW;          // 16384
constexpr size_t CHW   = (size_t)C * HW;      // 1,048,576
constexpr size_t TOT   = (size_t)B * CHW;     // 4,194,304
constexpr float SCALE  = 1.0f / 24.0f;        // 1/sqrt(C*9)

typedef _Float16 half8 __attribute__((ext_vector_type(8)));
typedef _Float16 half2t __attribute__((ext_vector_type(2)));
typedef float floatx4 __attribute__((ext_vector_type(4)));

// Weight arena layout (fp16), per conv: [KK*2 chunks][64 oc][32 ic] halfs.
// res convs (18 x 36864), mw1 (10 x 4096), mw3 (10 x 36864), mw5 (10 x 102400)
constexpr size_t WT_RES = 0;
constexpr size_t WT_M1  = 663552;
constexpr size_t WT_M3  = 704512;
constexpr size_t WT_M5  = 1073152;
constexpr size_t WT_TOT = 2097152;            // halfs = 4 MiB

// ---------------------------------------------------------------------------
// Transform all conv weights fp32 OIHW -> fp16 [t][oc][icw] arena.
// t = (kh*K+kw)*2 + h, ic = h*32 + icw.
// ---------------------------------------------------------------------------
__global__ __launch_bounds__(256) void wt_kernel(
    const float* __restrict__ rw, const float* __restrict__ mw1,
    const float* __restrict__ mw3, const float* __restrict__ mw5,
    _Float16* __restrict__ wt)
{
    int e = blockIdx.x * 256 + threadIdx.x;
    const float* src; int K; float scale; int l;
    if (e < (int)WT_M1) {
        int conv = e / 36864; l = e - conv * 36864;
        src = rw + (size_t)conv * 36864; K = 3; scale = SCALE;
    } else if (e < (int)WT_M3) {
        int e2 = e - (int)WT_M1; int conv = e2 / 4096; l = e2 - conv * 4096;
        src = mw1 + (size_t)conv * 4096; K = 1; scale = 1.f;
    } else if (e < (int)WT_M5) {
        int e2 = e - (int)WT_M3; int conv = e2 / 36864; l = e2 - conv * 36864;
        src = mw3 + (size_t)conv * 36864; K = 3; scale = 1.f;
    } else {
        int e2 = e - (int)WT_M5; int conv = e2 / 102400; l = e2 - conv * 102400;
        src = mw5 + (size_t)conv * 102400; K = 5; scale = 1.f;
    }
    int icw = l & 31, oc = (l >> 5) & 63, t = l >> 11;
    int kk = t >> 1, h = t & 1, ic = h * 32 + icw;
    int kh = kk / K, kw = kk - kh * K;
    float v = src[((oc * C + ic) * K + kh) * K + kw] * scale;
    wt[e] = (_Float16)v;
}

// ---------------------------------------------------------------------------
// Implicit-GEMM conv via fp16 MFMA. Block: 64 oc x 16x16 px, 256 thr (4 waves).
// Wave: 64 oc x 64 px (4 m-tiles x 4 n-groups of 16x16x32 MFMA).
// A (weights) read straight from the fp16 arena (L1/L2-cached, coalesced 16B/lane).
// B (input) staged fp32->fp16 channels-last in LDS, pixel stride 72 halfs.
// ACT: 0=none 1=relu 2=lrelu(0.01). cond scales input channels; res added at end.
// ---------------------------------------------------------------------------
template <int K, int ACT>
__global__ __launch_bounds__(256) void mconv_kernel(
    const float* __restrict__ in, const _Float16* __restrict__ wt,
    const float* __restrict__ bias, const float* __restrict__ cond,
    const float* __restrict__ res, float* __restrict__ out)
{
    constexpr int P = K / 2, IH = 16 + K - 1, IW = 16 + K - 1;
    constexpr int ICP = 72;                    // padded ic stride (144 B)
    __shared__ __align__(16) _Float16 s_in[IH * IW * ICP];

    const int tid = threadIdx.x;
    const int bx = blockIdx.x, b = blockIdx.y;
    const int y0 = (bx >> 3) * 16, x0 = (bx & 7) * 16;

    // ---- stage input tile (halo, zero-pad, cond-scale, fp16, channels-last)
    constexpr int NPAIR = IH * IW * 32;
    for (int idx = tid; idx < NPAIR; idx += 256) {
        int x = idx % IW;
        int tmp = idx / IW;
        int r = tmp % IH;
        int icp = tmp / IH;
        int gy = y0 + r - P, gx = x0 + x - P;
        float v0 = 0.f, v1 = 0.f;
        if (gy >= 0 && gy < H && gx >= 0 && gx < W) {
            size_t base = ((size_t)(b * C + 2 * icp) * H + gy) * W + gx;
            v0 = in[base];
            v1 = in[base + PLANE];
        }
        if (cond) {
            v0 *= cond[b * C + 2 * icp];
            v1 *= cond[b * C + 2 * icp + 1];
        }
        half2t pk = { (_Float16)v0, (_Float16)v1 };
        *(half2t*)&s_in[(r * IW + x) * ICP + 2 * icp] = pk;
    }
    __syncthreads();

    const int lane = tid & 63, wv = tid >> 6;
    const int l15 = lane & 15, quad = lane >> 4;

    floatx4 acc[4][4] = {};

    for (int kh = 0; kh < K; ++kh) {
#pragma unroll
        for (int kw = 0; kw < K; ++kw) {
#pragma unroll
            for (int h = 0; h < 2; ++h) {
                const int t = (kh * K + kw) * 2 + h;
                const _Float16* ap = wt + ((size_t)(t * 64 + l15) * 32 + quad * 8);
                half8 a0 = *(const half8*)(ap);
                half8 a1 = *(const half8*)(ap + 16 * 32);
                half8 a2 = *(const half8*)(ap + 32 * 32);
                half8 a3 = *(const half8*)(ap + 48 * 32);
                half8 bf[4];
#pragma unroll
                for (int ng = 0; ng < 4; ++ng) {
                    int row = 4 * wv + ng + kh, col = l15 + kw;
                    bf[ng] = *(const half8*)&s_in[(row * IW + col) * ICP + h * 32 + quad * 8];
                }
#pragma unroll
                for (int ng = 0; ng < 4; ++ng) {
                    acc[0][ng] = __builtin_amdgcn_mfma_f32_16x16x32_f16(a0, bf[ng], acc[0][ng], 0, 0, 0);
                    acc[1][ng] = __builtin_amdgcn_mfma_f32_16x16x32_f16(a1, bf[ng], acc[1][ng], 0, 0, 0);
                    acc[2][ng] = __builtin_amdgcn_mfma_f32_16x16x32_f16(a2, bf[ng], acc[2][ng], 0, 0, 0);
                    acc[3][ng] = __builtin_amdgcn_mfma_f32_16x16x32_f16(a3, bf[ng], acc[3][ng], 0, 0, 0);
                }
            }
        }
    }

    // ---- epilogue: D[oc = mt*16 + quad*4 + r][px = l15], rows 4*wv+ng
#pragma unroll
    for (int mt = 0; mt < 4; ++mt) {
#pragma unroll
        for (int r = 0; r < 4; ++r) {
            const int oc = mt * 16 + quad * 4 + r;
            const float bv = bias ? bias[oc] : 0.f;
#pragma unroll
            for (int ng = 0; ng < 4; ++ng) {
                const int y = y0 + 4 * wv + ng, x = x0 + l15;
                const size_t o = ((size_t)(b * C + oc) * H + y) * W + x;
                float v = acc[mt][ng][r] + bv;
                if (ACT == 1) v = fmaxf(v, 0.f);
                if (ACT == 2) v = v > 0.f ? v : 0.01f * v;
                if (res) v += res[o];
                out[o] = v;
            }
        }
    }
}

// ---------------------------------------------------------------------------
// Per-(b,c) max & mean over the 128x128 plane. One block per (b,c).
// ---------------------------------------------------------------------------
__global__ __launch_bounds__(256) void pool_kernel(
    const float* __restrict__ o, float* __restrict__ mx, float* __restrict__ av)
{
    const int bc = blockIdx.x;
    const float* p = o + (size_t)bc * PLANE;
    const int tid = threadIdx.x;
    float m = -INFINITY, s = 0.f;
    for (int i = tid; i < HW; i += 256) {
        float v = p[i];
        m = fmaxf(m, v);
        s += v;
    }
#pragma unroll
    for (int off = 32; off > 0; off >>= 1) {
        m = fmaxf(m, __shfl_down(m, off));
        s += __shfl_down(s, off);
    }
    __shared__ float sm[4], ss[4];
    if ((tid & 63) == 0) { sm[tid >> 6] = m; ss[tid >> 6] = s; }
    __syncthreads();
    if (tid == 0) {
        m = fmaxf(fmaxf(sm[0], sm[1]), fmaxf(sm[2], sm[3]));
        s = ss[0] + ss[1] + ss[2] + ss[3];
        mx[bc] = m;
        av[bc] = s * (1.f / HW);
    }
}

// Channel attention + FC1 gate -> Cg[b,c]. One block, 256 threads.
__global__ __launch_bounds__(256) void cg_kernel(
    const float* __restrict__ mx, const float* __restrict__ av,
    const float* __restrict__ caw1, const float* __restrict__ caw2,
    const float* __restrict__ fcw, const float* __restrict__ fcb,
    float* __restrict__ Cg)
{
    __shared__ float hid[2][4][4]; // which, b, h
    const int t = threadIdx.x;
    if (t < 32) {
        int which = t >> 4, b = (t >> 2) & 3, h = t & 3;
        const float* src = which ? av : mx;
        float s = 0.f;
        for (int i = 0; i < C; ++i) s += caw1[h * C + i] * src[b * C + i];
        hid[which][b][h] = fmaxf(s, 0.f);
    }
    __syncthreads();
    int b = t >> 6, c = t & 63;
    float s = 0.f;
#pragma unroll
    for (int h = 0; h < 4; ++h)
        s += caw2[c * 4 + h] * (hid[0][b][h] + hid[1][b][h]);
    float xll = 1.f / (1.f + expf(-s));
    Cg[t] = fcw[1] * (fcw[0] * xll + fcb[0]) + fcb[1];
}

// o = Cg[b,c] * acc
__global__ __launch_bounds__(256) void cgmul_kernel(
    const float* __restrict__ acc, const float* __restrict__ Cg, float* __restrict__ o)
{
    size_t i = (size_t)blockIdx.x * 256 + threadIdx.x;
    size_t e = i * 4;
    int bc = (int)(e / PLANE);
    float g = Cg[bc];
    float4 v = ((const float4*)acc)[i];
    v.x *= g; v.y *= g; v.z *= g; v.w *= g;
    ((float4*)o)[i] = v;
}

// out = o * map + x
__global__ __launch_bounds__(256) void final_kernel(
    const float* __restrict__ o, const float* __restrict__ mapp,
    const float* __restrict__ x, float* __restrict__ out)
{
    size_t i = (size_t)blockIdx.x * 256 + threadIdx.x;
    size_t e = i * 4;
    size_t b = e / CHW;
    size_t pos = e % PLANE;
    float4 ov = ((const float4*)o)[i];
    float4 xv = ((const float4*)x)[i];
    float4 mv = ((const float4*)(mapp + b * PLANE))[pos >> 2];
    float4 r;
    r.x = fmaf(ov.x, mv.x, xv.x);
    r.y = fmaf(ov.y, mv.y, xv.y);
    r.z = fmaf(ov.z, mv.z, xv.z);
    r.w = fmaf(ov.w, mv.w, xv.w);
    ((float4*)out)[i] = r;
}

extern "C" void kernel_launch(void* const* d_in, const int* in_sizes, int n_in,
                              void* d_out, int out_size, void* d_ws, size_t ws_size,
                              hipStream_t stream)
{
    const float* x    = (const float*)d_in[0];
    const float* cf1  = (const float*)d_in[1];
    const float* cf2  = (const float*)d_in[2];
    const float* mapp = (const float*)d_in[3];
    const float* rw   = (const float*)d_in[4];
    const float* rb   = (const float*)d_in[5];
    const float* mw1  = (const float*)d_in[6];
    const float* mb1  = (const float*)d_in[7];
    const float* mw3  = (const float*)d_in[8];
    const float* mb3  = (const float*)d_in[9];
    const float* mw5  = (const float*)d_in[10];
    const float* mb5  = (const float*)d_in[11];
    const float* caw1 = (const float*)d_in[12];
    const float* caw2 = (const float*)d_in[13];
    const float* fcw  = (const float*)d_in[14];
    const float* fcb  = (const float*)d_in[15];
    float* out = (float*)d_out;

    _Float16* wta = (_Float16*)d_ws;
    float* fbase  = (float*)((char*)d_ws + WT_TOT * sizeof(_Float16));
    float* buf_o   = fbase;
    float* buf_t   = fbase + TOT;
    float* buf_acc = fbase + 2 * TOT;
    float* st      = fbase + 3 * TOT;
    float* mx = st, *av = st + 256, *Cg = st + 512;

    // transform all weights -> fp16 arena
    wt_kernel<<<dim3((unsigned)(WT_TOT / 256)), 256, 0, stream>>>(rw, mw1, mw3, mw5, wta);

    const dim3 cgrid(64, B);
    const dim3 egrid((unsigned)(TOT / 1024));

    int mfe_j = 0;
    for (int i = 0; i < 9; ++i) {
        const float* condb = (i < 5) ? (cf1 + (size_t)i * 2 * B * C)
                                     : (cf2 + (size_t)(i - 5) * 2 * B * C);
        const float* in0 = (i == 0) ? x : buf_o;
        const _Float16* rw0 = wta + WT_RES + (size_t)(i * 2 + 0) * 36864;
        const _Float16* rw1 = wta + WT_RES + (size_t)(i * 2 + 1) * 36864;
        const float* rb0 = rb + (i * 2 + 0) * C;
        const float* rb1 = rb + (i * 2 + 1) * C;
        // r = relu(conv(o*cond0, w0*SCALE) + rb0)
        mconv_kernel<3, 1><<<cgrid, 256, 0, stream>>>(in0, rw0, rb0, condb, nullptr, buf_t);
        // o = conv(r*cond1, w1*SCALE) + rb1 + o
        mconv_kernel<3, 0><<<cgrid, 256, 0, stream>>>(buf_t, rw1, rb1, condb + B * C, in0, buf_o);

        if (i == 1 || i == 3 || i == 5 || i == 7 || i == 8) {
            int j = mfe_j++;
            const _Float16* w10 = wta + WT_M1 + (size_t)(j * 2 + 0) * 4096;
            const _Float16* w11 = wta + WT_M1 + (size_t)(j * 2 + 1) * 4096;
            const _Float16* w30 = wta + WT_M3 + (size_t)(j * 2 + 0) * 36864;
            const _Float16* w31 = wta + WT_M3 + (size_t)(j * 2 + 1) * 36864;
            const _Float16* w50 = wta + WT_M5 + (size_t)(j * 2 + 0) * 102400;
            const _Float16* w51 = wta + WT_M5 + (size_t)(j * 2 + 1) * 102400;
            const float* b10 = mb1 + (j * 2 + 0) * C, *b11 = mb1 + (j * 2 + 1) * C;
            const float* b30 = mb3 + (j * 2 + 0) * C, *b31 = mb3 + (j * 2 + 1) * C;
            const float* b50 = mb5 + (j * 2 + 0) * C, *b51 = mb5 + (j * 2 + 1) * C;

            // channel-attention stats on buf_o (independent of branch convs)
            pool_kernel<<<dim3(B * C), 256, 0, stream>>>(buf_o, mx, av);
            cg_kernel<<<1, 256, 0, stream>>>(mx, av, caw1 + j * 4 * C, caw2 + j * C * 4,
                                             fcw + j * 2, fcb + j * 2, Cg);

            // x1 path (1x1): acc = conv(lrelu(conv(o)))
            mconv_kernel<1, 2><<<cgrid, 256, 0, stream>>>(buf_o, w10, b10, nullptr, nullptr, buf_t);
            mconv_kernel<1, 0><<<cgrid, 256, 0, stream>>>(buf_t, w11, b11, nullptr, nullptr, buf_acc);
            // x3 path: acc += ...
            mconv_kernel<3, 2><<<cgrid, 256, 0, stream>>>(buf_o, w30, b30, nullptr, nullptr, buf_t);
            mconv_kernel<3, 0><<<cgrid, 256, 0, stream>>>(buf_t, w31, b31, nullptr, buf_acc, buf_acc);
            // x5 path: acc += ...
            mconv_kernel<5, 2><<<cgrid, 256, 0, stream>>>(buf_o, w50, b50, nullptr, nullptr, buf_t);
            mconv_kernel<5, 0><<<cgrid, 256, 0, stream>>>(buf_t, w51, b51, nullptr, buf_acc, buf_acc);

            // o = Cg * (x1+x3+x5)
            cgmul_kernel<<<egrid, 256, 0, stream>>>(buf_acc, Cg, buf_o);
        }
    }
    // out = o * map + x
    final_kernel<<<egrid, 256, 0, stream>>>(buf_o, mapp, x, out);
}

// Round 3
// 1549.808 us; speedup vs baseline: 4.2131x; 1.3018x over previous
//
#include <hip/hip_runtime.h>
#include <math.h>

// Problem constants (PMS_1): B=4, C=64, H=W=128
constexpr int B = 4, C = 64, H = 128, W = 128;
constexpr int HW = H * W;
constexpr size_t PLANE = (size_t)HW;          // 16384
constexpr size_t CHW   = (size_t)C * HW;      // 1,048,576
constexpr size_t TOT   = (size_t)B * CHW;     // 4,194,304
constexpr float SCALE  = 1.0f / 24.0f;        // 1/sqrt(C*9)

typedef _Float16 half8 __attribute__((ext_vector_type(8)));
typedef _Float16 half2t __attribute__((ext_vector_type(2)));
typedef float floatx4 __attribute__((ext_vector_type(4)));

// Weight arena layout (fp16), per conv: [KK*2 chunks][64 oc][32 ic] halfs.
constexpr size_t WT_RES = 0;
constexpr size_t WT_M1  = 663552;
constexpr size_t WT_M3  = 704512;
constexpr size_t WT_M5  = 1073152;
constexpr size_t WT_TOT = 2097152;            // halfs = 4 MiB

__global__ __launch_bounds__(256) void wt_kernel(
    const float* __restrict__ rw, const float* __restrict__ mw1,
    const float* __restrict__ mw3, const float* __restrict__ mw5,
    _Float16* __restrict__ wt)
{
    int e = blockIdx.x * 256 + threadIdx.x;
    const float* src; int K; float scale; int l;
    if (e < (int)WT_M1) {
        int conv = e / 36864; l = e - conv * 36864;
        src = rw + (size_t)conv * 36864; K = 3; scale = SCALE;
    } else if (e < (int)WT_M3) {
        int e2 = e - (int)WT_M1; int conv = e2 / 4096; l = e2 - conv * 4096;
        src = mw1 + (size_t)conv * 4096; K = 1; scale = 1.f;
    } else if (e < (int)WT_M5) {
        int e2 = e - (int)WT_M3; int conv = e2 / 36864; l = e2 - conv * 36864;
        src = mw3 + (size_t)conv * 36864; K = 3; scale = 1.f;
    } else {
        int e2 = e - (int)WT_M5; int conv = e2 / 102400; l = e2 - conv * 102400;
        src = mw5 + (size_t)conv * 102400; K = 5; scale = 1.f;
    }
    int icw = l & 31, oc = (l >> 5) & 63, t = l >> 11;
    int kk = t >> 1, h = t & 1, ic = h * 32 + icw;
    int kh = kk / K, kw = kk - kh * K;
    float v = src[((oc * C + ic) * K + kh) * K + kw] * scale;
    wt[e] = (_Float16)v;
}

// ---------------------------------------------------------------------------
// Implicit-GEMM conv via fp16 MFMA.
// Block: 256 thr (4 waves), tile 8x16 px x 64 oc. Wave: 64 oc x 32 px
// (rows 2w,2w+1), acc[4][2]. Grid 512 -> 2 blocks/CU, 8 waves/CU.
// LDS input tile: [px][ic] with px stride 66 halfs (33 dwords, odd) ->
// B-fragment b32 reads are 2-way bank-aliased = conflict-free.
// Staged from even-aligned col origin (CO) so staging uses float2 loads.
// ---------------------------------------------------------------------------
template <int K, int ACT>
__global__ __launch_bounds__(256, 2) void mconv_kernel(
    const float* __restrict__ in, const _Float16* __restrict__ wt,
    const float* __restrict__ bias, const float* __restrict__ cond,
    const float* __restrict__ res, float* __restrict__ out)
{
    constexpr int P = K / 2;
    constexpr int IHs = 8 + K - 1;
    constexpr int IWs = (K == 1) ? 16 : 20;      // even-origin staging window
    constexpr int CO  = (K == 1) ? 0 : 2;        // staged col 0 == x0 - CO
    constexpr int XP  = IWs / 2;                 // float2 cols
    constexpr int NPX2 = IHs * XP;
    constexpr int NITEM = NPX2 * 32;             // x 32 ic-pairs
    __shared__ unsigned int s_u[IHs * IWs * 33]; // 33 dwords per px

    const int tid = threadIdx.x;
    const int bx = blockIdx.x, b = blockIdx.y;
    const int y0 = (bx >> 3) * 8, x0 = (bx & 7) * 16;

    // ---- stage input tile (halo, zero-pad, cond-scale, fp16, [px][ic])
    for (int idx = tid; idx < NITEM; idx += 256) {
        int icp = idx / NPX2;
        int rem = idx - icp * NPX2;
        int r = rem / XP;
        int xp = rem - r * XP;
        int gy = y0 + r - P, gx = x0 + 2 * xp - CO;
        float2 va = make_float2(0.f, 0.f), vb = make_float2(0.f, 0.f);
        if (gy >= 0 && gy < H && gx >= 0 && gx < W) {
            size_t base = ((size_t)(b * C + 2 * icp) * H + gy) * W + gx;
            va = *(const float2*)&in[base];
            vb = *(const float2*)&in[base + PLANE];
        }
        if (cond) {
            float c0 = cond[b * C + 2 * icp], c1 = cond[b * C + 2 * icp + 1];
            va.x *= c0; va.y *= c0; vb.x *= c1; vb.y *= c1;
        }
        int px = r * IWs + 2 * xp;
        half2t p0 = { (_Float16)va.x, (_Float16)vb.x };
        half2t p1 = { (_Float16)va.y, (_Float16)vb.y };
        s_u[px * 33 + icp]       = __builtin_bit_cast(unsigned int, p0);
        s_u[(px + 1) * 33 + icp] = __builtin_bit_cast(unsigned int, p1);
    }
    __syncthreads();

    const int lane = tid & 63, wv = tid >> 6;
    const int l15 = lane & 15, q = lane >> 4;

    floatx4 acc[4][2] = {};

    for (int kh = 0; kh < K; ++kh) {
#pragma unroll
        for (int kw = 0; kw < K; ++kw) {
#pragma unroll
            for (int h = 0; h < 2; ++h) {
                const int t = (kh * K + kw) * 2 + h;
                const _Float16* ap = wt + ((size_t)(t * 64 + l15) * 32 + q * 8);
                half8 a0 = *(const half8*)(ap);
                half8 a1 = *(const half8*)(ap + 16 * 32);
                half8 a2 = *(const half8*)(ap + 32 * 32);
                half8 a3 = *(const half8*)(ap + 48 * 32);
                half8 bf[2];
#pragma unroll
                for (int ng = 0; ng < 2; ++ng) {
                    int row = 2 * wv + ng + kh;
                    int col = l15 + kw - P + CO;
                    int base = (row * IWs + col) * 33 + h * 16 + q * 4;
                    uint4 u;
                    u.x = s_u[base + 0];
                    u.y = s_u[base + 1];
                    u.z = s_u[base + 2];
                    u.w = s_u[base + 3];
                    bf[ng] = __builtin_bit_cast(half8, u);
                }
#pragma unroll
                for (int ng = 0; ng < 2; ++ng) {
                    acc[0][ng] = __builtin_amdgcn_mfma_f32_16x16x32_f16(a0, bf[ng], acc[0][ng], 0, 0, 0);
                    acc[1][ng] = __builtin_amdgcn_mfma_f32_16x16x32_f16(a1, bf[ng], acc[1][ng], 0, 0, 0);
                    acc[2][ng] = __builtin_amdgcn_mfma_f32_16x16x32_f16(a2, bf[ng], acc[2][ng], 0, 0, 0);
                    acc[3][ng] = __builtin_amdgcn_mfma_f32_16x16x32_f16(a3, bf[ng], acc[3][ng], 0, 0, 0);
                }
            }
        }
    }

    // ---- epilogue: D[oc = mt*16 + q*4 + r][px = l15], rows y0 + 2*wv + ng
#pragma unroll
    for (int mt = 0; mt < 4; ++mt) {
#pragma unroll
        for (int r = 0; r < 4; ++r) {
            const int oc = mt * 16 + q * 4 + r;
            const float bv = bias ? bias[oc] : 0.f;
#pragma unroll
            for (int ng = 0; ng < 2; ++ng) {
                const int y = y0 + 2 * wv + ng, x = x0 + l15;
                const size_t o = ((size_t)(b * C + oc) * H + y) * W + x;
                float v = acc[mt][ng][r] + bv;
                if (ACT == 1) v = fmaxf(v, 0.f);
                if (ACT == 2) v = v > 0.f ? v : 0.01f * v;
                if (res) v += res[o];
                out[o] = v;
            }
        }
    }
}

// ---------------------------------------------------------------------------
__global__ __launch_bounds__(256) void pool_kernel(
    const float* __restrict__ o, float* __restrict__ mx, float* __restrict__ av)
{
    const int bc = blockIdx.x;
    const float* p = o + (size_t)bc * PLANE;
    const int tid = threadIdx.x;
    float m = -INFINITY, s = 0.f;
    for (int i = tid; i < HW; i += 256) {
        float v = p[i];
        m = fmaxf(m, v);
        s += v;
    }
#pragma unroll
    for (int off = 32; off > 0; off >>= 1) {
        m = fmaxf(m, __shfl_down(m, off));
        s += __shfl_down(s, off);
    }
    __shared__ float sm[4], ss[4];
    if ((tid & 63) == 0) { sm[tid >> 6] = m; ss[tid >> 6] = s; }
    __syncthreads();
    if (tid == 0) {
        m = fmaxf(fmaxf(sm[0], sm[1]), fmaxf(sm[2], sm[3]));
        s = ss[0] + ss[1] + ss[2] + ss[3];
        mx[bc] = m;
        av[bc] = s * (1.f / HW);
    }
}

__global__ __launch_bounds__(256) void cg_kernel(
    const float* __restrict__ mx, const float* __restrict__ av,
    const float* __restrict__ caw1, const float* __restrict__ caw2,
    const float* __restrict__ fcw, const float* __restrict__ fcb,
    float* __restrict__ Cg)
{
    __shared__ float hid[2][4][4];
    const int t = threadIdx.x;
    if (t < 32) {
        int which = t >> 4, b = (t >> 2) & 3, h = t & 3;
        const float* src = which ? av : mx;
        float s = 0.f;
        for (int i = 0; i < C; ++i) s += caw1[h * C + i] * src[b * C + i];
        hid[which][b][h] = fmaxf(s, 0.f);
    }
    __syncthreads();
    int b = t >> 6, c = t & 63;
    float s = 0.f;
#pragma unroll
    for (int h = 0; h < 4; ++h)
        s += caw2[c * 4 + h] * (hid[0][b][h] + hid[1][b][h]);
    float xll = 1.f / (1.f + expf(-s));
    Cg[t] = fcw[1] * (fcw[0] * xll + fcb[0]) + fcb[1];
}

__global__ __launch_bounds__(256) void cgmul_kernel(
    const float* __restrict__ acc, const float* __restrict__ Cg, float* __restrict__ o)
{
    size_t i = (size_t)blockIdx.x * 256 + threadIdx.x;
    size_t e = i * 4;
    int bc = (int)(e / PLANE);
    float g = Cg[bc];
    float4 v = ((const float4*)acc)[i];
    v.x *= g; v.y *= g; v.z *= g; v.w *= g;
    ((float4*)o)[i] = v;
}

__global__ __launch_bounds__(256) void final_kernel(
    const float* __restrict__ o, const float* __restrict__ mapp,
    const float* __restrict__ x, float* __restrict__ out)
{
    size_t i = (size_t)blockIdx.x * 256 + threadIdx.x;
    size_t e = i * 4;
    size_t b = e / CHW;
    size_t pos = e % PLANE;
    float4 ov = ((const float4*)o)[i];
    float4 xv = ((const float4*)x)[i];
    float4 mv = ((const float4*)(mapp + b * PLANE))[pos >> 2];
    float4 r;
    r.x = fmaf(ov.x, mv.x, xv.x);
    r.y = fmaf(ov.y, mv.y, xv.y);
    r.z = fmaf(ov.z, mv.z, xv.z);
    r.w = fmaf(ov.w, mv.w, xv.w);
    ((float4*)out)[i] = r;
}

extern "C" void kernel_launch(void* const* d_in, const int* in_sizes, int n_in,
                              void* d_out, int out_size, void* d_ws, size_t ws_size,
                              hipStream_t stream)
{
    const float* x    = (const float*)d_in[0];
    const float* cf1  = (const float*)d_in[1];
    const float* cf2  = (const float*)d_in[2];
    const float* mapp = (const float*)d_in[3];
    const float* rw   = (const float*)d_in[4];
    const float* rb   = (const float*)d_in[5];
    const float* mw1  = (const float*)d_in[6];
    const float* mb1  = (const float*)d_in[7];
    const float* mw3  = (const float*)d_in[8];
    const float* mb3  = (const float*)d_in[9];
    const float* mw5  = (const float*)d_in[10];
    const float* mb5  = (const float*)d_in[11];
    const float* caw1 = (const float*)d_in[12];
    const float* caw2 = (const float*)d_in[13];
    const float* fcw  = (const float*)d_in[14];
    const float* fcb  = (const float*)d_in[15];
    float* out = (float*)d_out;

    _Float16* wta = (_Float16*)d_ws;
    float* fbase  = (float*)((char*)d_ws + WT_TOT * sizeof(_Float16));
    float* buf_o   = fbase;
    float* buf_t   = fbase + TOT;
    float* buf_acc = fbase + 2 * TOT;
    float* st      = fbase + 3 * TOT;
    float* mx = st, *av = st + 256, *Cg = st + 512;

    wt_kernel<<<dim3((unsigned)(WT_TOT / 256)), 256, 0, stream>>>(rw, mw1, mw3, mw5, wta);

    const dim3 cgrid(128, B);   // 16x8 tiles of 8x16 px
    const dim3 egrid((unsigned)(TOT / 1024));

    int mfe_j = 0;
    for (int i = 0; i < 9; ++i) {
        const float* condb = (i < 5) ? (cf1 + (size_t)i * 2 * B * C)
                                     : (cf2 + (size_t)(i - 5) * 2 * B * C);
        const float* in0 = (i == 0) ? x : buf_o;
        const _Float16* rw0 = wta + WT_RES + (size_t)(i * 2 + 0) * 36864;
        const _Float16* rw1 = wta + WT_RES + (size_t)(i * 2 + 1) * 36864;
        const float* rb0 = rb + (i * 2 + 0) * C;
        const float* rb1 = rb + (i * 2 + 1) * C;
        mconv_kernel<3, 1><<<cgrid, 256, 0, stream>>>(in0, rw0, rb0, condb, nullptr, buf_t);
        mconv_kernel<3, 0><<<cgrid, 256, 0, stream>>>(buf_t, rw1, rb1, condb + B * C, in0, buf_o);

        if (i == 1 || i == 3 || i == 5 || i == 7 || i == 8) {
            int j = mfe_j++;
            const _Float16* w10 = wta + WT_M1 + (size_t)(j * 2 + 0) * 4096;
            const _Float16* w11 = wta + WT_M1 + (size_t)(j * 2 + 1) * 4096;
            const _Float16* w30 = wta + WT_M3 + (size_t)(j * 2 + 0) * 36864;
            const _Float16* w31 = wta + WT_M3 + (size_t)(j * 2 + 1) * 36864;
            const _Float16* w50 = wta + WT_M5 + (size_t)(j * 2 + 0) * 102400;
            const _Float16* w51 = wta + WT_M5 + (size_t)(j * 2 + 1) * 102400;
            const float* b10 = mb1 + (j * 2 + 0) * C, *b11 = mb1 + (j * 2 + 1) * C;
            const float* b30 = mb3 + (j * 2 + 0) * C, *b31 = mb3 + (j * 2 + 1) * C;
            const float* b50 = mb5 + (j * 2 + 0) * C, *b51 = mb5 + (j * 2 + 1) * C;

            pool_kernel<<<dim3(B * C), 256, 0, stream>>>(buf_o, mx, av);
            cg_kernel<<<1, 256, 0, stream>>>(mx, av, caw1 + j * 4 * C, caw2 + j * C * 4,
                                             fcw + j * 2, fcb + j * 2, Cg);

            mconv_kernel<1, 2><<<cgrid, 256, 0, stream>>>(buf_o, w10, b10, nullptr, nullptr, buf_t);
            mconv_kernel<1, 0><<<cgrid, 256, 0, stream>>>(buf_t, w11, b11, nullptr, nullptr, buf_acc);
            mconv_kernel<3, 2><<<cgrid, 256, 0, stream>>>(buf_o, w30, b30, nullptr, nullptr, buf_t);
            mconv_kernel<3, 0><<<cgrid, 256, 0, stream>>>(buf_t, w31, b31, nullptr, buf_acc, buf_acc);
            mconv_kernel<5, 2><<<cgrid, 256, 0, stream>>>(buf_o, w50, b50, nullptr, nullptr, buf_t);
            mconv_kernel<5, 0><<<cgrid, 256, 0, stream>>>(buf_t, w51, b51, nullptr, buf_acc, buf_acc);

            cgmul_kernel<<<egrid, 256, 0, stream>>>(buf_acc, Cg, buf_o);
        }
    }
    final_kernel<<<egrid, 256, 0, stream>>>(buf_o, mapp, x, out);
}